// Round 5
// baseline (145.776 us; speedup 1.0000x reference)
//
#include <hip/hip_runtime.h>
#include <math.h>

namespace {

constexpr int SOUT = 12;    // (14-3)/1+1
constexpr int OCAP = 32;
constexpr int PD   = 16;    // 4x4 pose
constexpr int NI   = 288;   // 3*3*32
constexpr int NPOS = 4 * SOUT * SOUT;  // 576
constexpr float EPSF = 1e-9f;
constexpr size_t POSE_OUT = (size_t)NPOS * OCAP * PD;  // 294912

// One block per output position. 512 threads = 8 waves.
// lane -> (o = lane&31, half = lane>>5); per step a wave handles 2 input caps.
// NOTE: hipcc treats the 2nd launch_bounds arg as min BLOCKS/CU (R3/R4 evidence:
// caps of 40/64 VGPR at args 6/4). Use 2 -> 128 VGPR cap -> no scratch spill.
__global__ __launch_bounds__(512, 2)
void caps_em_fused(const float* __restrict__ pose_in,   // [4,14,14,32,16]
                   const float* __restrict__ act_in,    // [4,14,14,32]
                   const float* __restrict__ wmat,      // [288,32,16]
                   const float* __restrict__ beta_v,    // [32]
                   const float* __restrict__ beta_a,    // [32]
                   float* __restrict__ out)             // pose ++ act
{
    __shared__ __align__(16) float sP[NI * PD];   // 18 KB patch poses
    __shared__ float sA[NI];                      // patch activations
    __shared__ float sInv2[OCAP][PD + 1];         // 1/(2*var)
    __shared__ float sNeg[OCAP][PD + 1];          // -2*mean/(2*var)
    __shared__ float sBias[OCAP];                 // log(oact+EPS) - lt - C0
    __shared__ float sRed[4][33][33];             // two-round cross-wave partials

    const int n  = blockIdx.x;
    const int b  = n / (SOUT * SOUT);
    const int yx = n % (SOUT * SOUT);
    const int y  = yx / SOUT;
    const int x  = yx % SOUT;

    const int t    = threadIdx.x;
    const int wave = t >> 6;            // 0..7
    const int lane = t & 63;
    const int o    = lane & 31;
    const int half = lane >> 5;

    // ---- stage 3x3 patch into LDS (coalesced float4) ----
    {
        const float4* src = reinterpret_cast<const float4*>(pose_in);
        float4* dst = reinterpret_cast<float4*>(sP);
        for (int u = t; u < NI * 4; u += 512) {   // 1152 float4
            const int k = u >> 7, idx = u & 127;  // cell, float4-within-cell
            const int ki = k / 3, kj = k - ki * 3;
            const int cell = (b * 14 + y + ki) * 14 + (x + kj);
            dst[u] = src[(size_t)cell * 128 + idx];
        }
        for (int u = t; u < NI; u += 512) {
            const int k = u >> 5, c = u & 31;
            const int ki = k / 3, kj = k - ki * 3;
            const int cell = (b * 14 + y + ki) * 14 + (x + kj);
            sA[u] = act_in[(size_t)cell * 32 + c];
        }
    }
    __syncthreads();

    for (int sweep = 0; sweep < 3; ++sweep) {
        const float bias_r = (sweep > 0) ? sBias[o] : 0.f;

        float s1[PD], s2[PD];
        float s0 = 0.f;
        #pragma unroll
        for (int d = 0; d < PD; ++d) { s1[d] = 0.f; s2[d] = 0.f; }

        #pragma unroll 1
        for (int step = 0; step < NI / 16; ++step) {   // 18 steps
            const int i = step * 16 + wave * 2 + half;

            // votes[p,r] = sum_q P[p,q]*W[q,r], q-outer: only one W row (4 regs)
            // live at a time; P row loaded via LDS broadcast.
            float v[PD];
            const float* pr = &sP[i * PD];
            const float* wr = wmat + ((size_t)i * OCAP + o) * PD;
            {
                const float4 w0 = *reinterpret_cast<const float4*>(&wr[0]);
                const float4 p0 = *reinterpret_cast<const float4*>(&pr[0]);
                const float4 p1 = *reinterpret_cast<const float4*>(&pr[4]);
                const float4 p2 = *reinterpret_cast<const float4*>(&pr[8]);
                const float4 p3 = *reinterpret_cast<const float4*>(&pr[12]);
                v[0]  = p0.x * w0.x; v[1]  = p0.x * w0.y; v[2]  = p0.x * w0.z; v[3]  = p0.x * w0.w;
                v[4]  = p1.x * w0.x; v[5]  = p1.x * w0.y; v[6]  = p1.x * w0.z; v[7]  = p1.x * w0.w;
                v[8]  = p2.x * w0.x; v[9]  = p2.x * w0.y; v[10] = p2.x * w0.z; v[11] = p2.x * w0.w;
                v[12] = p3.x * w0.x; v[13] = p3.x * w0.y; v[14] = p3.x * w0.z; v[15] = p3.x * w0.w;
                const float4 w1 = *reinterpret_cast<const float4*>(&wr[4]);
                v[0]  = fmaf(p0.y, w1.x, v[0]);  v[1]  = fmaf(p0.y, w1.y, v[1]);
                v[2]  = fmaf(p0.y, w1.z, v[2]);  v[3]  = fmaf(p0.y, w1.w, v[3]);
                v[4]  = fmaf(p1.y, w1.x, v[4]);  v[5]  = fmaf(p1.y, w1.y, v[5]);
                v[6]  = fmaf(p1.y, w1.z, v[6]);  v[7]  = fmaf(p1.y, w1.w, v[7]);
                v[8]  = fmaf(p2.y, w1.x, v[8]);  v[9]  = fmaf(p2.y, w1.y, v[9]);
                v[10] = fmaf(p2.y, w1.z, v[10]); v[11] = fmaf(p2.y, w1.w, v[11]);
                v[12] = fmaf(p3.y, w1.x, v[12]); v[13] = fmaf(p3.y, w1.y, v[13]);
                v[14] = fmaf(p3.y, w1.z, v[14]); v[15] = fmaf(p3.y, w1.w, v[15]);
                const float4 w2 = *reinterpret_cast<const float4*>(&wr[8]);
                v[0]  = fmaf(p0.z, w2.x, v[0]);  v[1]  = fmaf(p0.z, w2.y, v[1]);
                v[2]  = fmaf(p0.z, w2.z, v[2]);  v[3]  = fmaf(p0.z, w2.w, v[3]);
                v[4]  = fmaf(p1.z, w2.x, v[4]);  v[5]  = fmaf(p1.z, w2.y, v[5]);
                v[6]  = fmaf(p1.z, w2.z, v[6]);  v[7]  = fmaf(p1.z, w2.w, v[7]);
                v[8]  = fmaf(p2.z, w2.x, v[8]);  v[9]  = fmaf(p2.z, w2.y, v[9]);
                v[10] = fmaf(p2.z, w2.z, v[10]); v[11] = fmaf(p2.z, w2.w, v[11]);
                v[12] = fmaf(p3.z, w2.x, v[12]); v[13] = fmaf(p3.z, w2.y, v[13]);
                v[14] = fmaf(p3.z, w2.z, v[14]); v[15] = fmaf(p3.z, w2.w, v[15]);
                const float4 w3 = *reinterpret_cast<const float4*>(&wr[12]);
                v[0]  = fmaf(p0.w, w3.x, v[0]);  v[1]  = fmaf(p0.w, w3.y, v[1]);
                v[2]  = fmaf(p0.w, w3.z, v[2]);  v[3]  = fmaf(p0.w, w3.w, v[3]);
                v[4]  = fmaf(p1.w, w3.x, v[4]);  v[5]  = fmaf(p1.w, w3.y, v[5]);
                v[6]  = fmaf(p1.w, w3.z, v[6]);  v[7]  = fmaf(p1.w, w3.w, v[7]);
                v[8]  = fmaf(p2.w, w3.x, v[8]);  v[9]  = fmaf(p2.w, w3.y, v[9]);
                v[10] = fmaf(p2.w, w3.z, v[10]); v[11] = fmaf(p2.w, w3.w, v[11]);
                v[12] = fmaf(p3.w, w3.x, v[12]); v[13] = fmaf(p3.w, w3.y, v[13]);
                v[14] = fmaf(p3.w, w3.z, v[14]); v[15] = fmaf(p3.w, w3.w, v[15]);
            }

            const float a_i = sA[i];
            float rrp;
            if (sweep == 0) {
                rrp = a_i * (1.0f / 32.0f);            // uniform rr = 1/O
            } else {
                // ts = sum_d (v-m)^2/(2var) expanded: v*(v*inv2 - 2*m*inv2), C0 in bias
                float ts = 0.f;
                #pragma unroll
                for (int d = 0; d < PD; ++d) {
                    const float h = fmaf(v[d], sInv2[o][d], sNeg[o][d]);
                    ts = fmaf(v[d], h, ts);
                }
                float zz = bias_r - ts;
                float m = zz;
                #pragma unroll
                for (int msk = 16; msk >= 1; msk >>= 1)
                    m = fmaxf(m, __shfl_xor(m, msk, 32));
                const float e = __expf(zz - m);
                float es = e;
                #pragma unroll
                for (int msk = 16; msk >= 1; msk >>= 1)
                    es += __shfl_xor(es, msk, 32);
                rrp = __fdividef(e, es) * a_i;         // rr * i_act
            }

            s0 += rrp;
            #pragma unroll
            for (int d = 0; d < PD; ++d) {
                const float rv = rrp * v[d];
                s1[d] = fmaf(rrp, v[d], s1[d]);
                s2[d] = fmaf(rv, v[d], s2[d]);
            }
        }

        // fold the two halves (same o) within each wave
        #pragma unroll
        for (int d = 0; d < PD; ++d) {
            s1[d] += __shfl_xor(s1[d], 32, 64);
            s2[d] += __shfl_xor(s2[d], 32, 64);
        }
        s0 += __shfl_xor(s0, 32, 64);

        // two-round cross-wave reduction into sRed[4][33][33]
        if (wave < 4 && half == 0) {
            #pragma unroll
            for (int d = 0; d < PD; ++d) {
                sRed[wave][d][o]      = s1[d];
                sRed[wave][16 + d][o] = s2[d];
            }
            sRed[wave][32][o] = s0;
        }
        __syncthreads();
        if (wave >= 4 && half == 0) {
            #pragma unroll
            for (int d = 0; d < PD; ++d) {
                sRed[wave - 4][d][o]      += s1[d];
                sRed[wave - 4][16 + d][o] += s2[d];
            }
            sRed[wave - 4][32][o] += s0;
        }
        __syncthreads();

        // ---- M-step on waves 0-3: thread = (o, d-pair) ----
        if (t < 256) {
            const int oo = t >> 3, dp = t & 7, d0 = dp * 2;
            float S0 = 0.f, S1a = 0.f, S1b = 0.f, S2a = 0.f, S2b = 0.f;
            #pragma unroll
            for (int r = 0; r < 4; ++r) {
                S0  += sRed[r][32][oo];
                S1a += sRed[r][d0][oo];
                S1b += sRed[r][d0 + 1][oo];
                S2a += sRed[r][16 + d0][oo];
                S2b += sRed[r][17 + d0][oo];
            }
            const float inv = 1.f / S0;
            const float m0 = S1a * inv, m1 = S1b * inv;
            const float v0 = fmaxf(fmaf(-m0, m0, S2a * inv), 0.f);
            const float v1 = fmaxf(fmaf(-m1, m1, S2b * inv), 0.f);
            if (sweep == 2) {
                float2 pv; pv.x = m0; pv.y = m1;
                *reinterpret_cast<float2*>(out + (size_t)n * (OCAP * PD) + oo * PD + d0) = pv;
            }
            const float i20 = 0.5f / fmaxf(v0, 1e-30f);
            const float i21 = 0.5f / fmaxf(v1, 1e-30f);
            float llocal = __logf(sqrtf(v0) + EPSF) + __logf(sqrtf(v1) + EPSF);
            float c0l    = m0 * m0 * i20 + m1 * m1 * i21;
            if (sweep < 2) {
                sInv2[oo][d0]     = i20;
                sInv2[oo][d0 + 1] = i21;
                sNeg[oo][d0]      = -2.f * m0 * i20;
                sNeg[oo][d0 + 1]  = -2.f * m1 * i21;
            }
            // 8-lane reductions over d-pairs
            #pragma unroll
            for (int msk = 1; msk <= 4; msk <<= 1) {
                llocal += __shfl_xor(llocal, msk, 8);
                c0l    += __shfl_xor(c0l,    msk, 8);
            }
            if (dp == 0) {
                const float lt   = llocal;
                const float cost = S0 * fmaf(16.f, beta_v[oo], lt);
                const float invtemp = 1.0f + (float)sweep;       // 1,2,3
                const float oact = 1.f / (1.f + __expf(-invtemp * (beta_a[oo] - cost)));
                if (sweep < 2)
                    sBias[oo] = __logf(oact + EPSF) - lt - c0l;
                else
                    out[POSE_OUT + (size_t)n * OCAP + oo] = oact;
            }
        }
        __syncthreads();
    }
}

} // namespace

extern "C" void kernel_launch(void* const* d_in, const int* in_sizes, int n_in,
                              void* d_out, int out_size, void* d_ws, size_t ws_size,
                              hipStream_t stream) {
    const float* pose_in = (const float*)d_in[0];
    const float* act_in  = (const float*)d_in[1];
    const float* wmat    = (const float*)d_in[2];
    const float* beta_v  = (const float*)d_in[3];
    const float* beta_a  = (const float*)d_in[4];
    float* out = (float*)d_out;

    caps_em_fused<<<dim3(NPOS), dim3(512), 0, stream>>>(
        pose_in, act_in, wmat, beta_v, beta_a, out);
}

// Round 6
// 117.857 us; speedup vs baseline: 1.2369x; 1.2369x over previous
//
#include <hip/hip_runtime.h>
#include <math.h>

namespace {

constexpr int SOUT = 12;    // (14-3)/1+1
constexpr int OCAP = 32;
constexpr int PD   = 16;    // 4x4 pose
constexpr int NI   = 288;   // 3*3*32
constexpr int NPOS = 4 * SOUT * SOUT;  // 576
constexpr float EPSF = 1e-9f;
constexpr size_t POSE_OUT = (size_t)NPOS * OCAP * PD;  // 294912

// Immediate-offset ds_swizzle butterfly within 32-lane groups:
// lane' = (lane & 0x1F) ^ msk   (BitMode: offset = (xor<<10) | and=0x1F)
#define SWZ(x, msk) __int_as_float(__builtin_amdgcn_ds_swizzle(__float_as_int(x), ((msk) << 10) | 0x1F))

__device__ __forceinline__ void loadW(const float* __restrict__ p, float (&W)[16]) {
    const float4 w0 = *reinterpret_cast<const float4*>(p);
    const float4 w1 = *reinterpret_cast<const float4*>(p + 4);
    const float4 w2 = *reinterpret_cast<const float4*>(p + 8);
    const float4 w3 = *reinterpret_cast<const float4*>(p + 12);
    W[0]=w0.x; W[1]=w0.y; W[2]=w0.z; W[3]=w0.w;
    W[4]=w1.x; W[5]=w1.y; W[6]=w1.z; W[7]=w1.w;
    W[8]=w2.x; W[9]=w2.y; W[10]=w2.z; W[11]=w2.w;
    W[12]=w3.x; W[13]=w3.y; W[14]=w3.z; W[15]=w3.w;
}

// votes[p,r] = sum_q P[p,q] * W[q,r]
__device__ __forceinline__ void vote16(const float* __restrict__ pr, const float (&W)[16], float (&v)[16]) {
    #pragma unroll
    for (int p = 0; p < 4; ++p) {
        const float4 pv = *reinterpret_cast<const float4*>(pr + p * 4);
        #pragma unroll
        for (int r = 0; r < 4; ++r)
            v[p*4+r] = fmaf(pv.x, W[r], fmaf(pv.y, W[4+r], fmaf(pv.z, W[8+r], pv.w * W[12+r])));
    }
}

// One block per output position. 256 threads = 4 waves.
// woff = t>>5 (0..7) selects the input capsule slot; o = t&31 the output capsule.
// Per pair-step a block covers 16 input capsules (8 slots x 2 unrolled steps).
__global__ __launch_bounds__(256, 2)
void caps_em_fused(const float* __restrict__ pose_in,   // [4,14,14,32,16]
                   const float* __restrict__ act_in,    // [4,14,14,32]
                   const float* __restrict__ wmat,      // [288,32,16]
                   const float* __restrict__ beta_v,    // [32]
                   const float* __restrict__ beta_a,    // [32]
                   float* __restrict__ out)             // pose ++ act
{
    __shared__ __align__(16) float sP[NI * PD];   // 18 KB patch poses
    __shared__ float sA[NI];                      // patch activations
    __shared__ __align__(16) float sInv2[OCAP][PD];  // 1/(2*var)
    __shared__ __align__(16) float sNeg[OCAP][PD];   // -2*mean/(2*var)
    __shared__ float sBias[OCAP];                 // log(oact+EPS) - lt - C0
    __shared__ float sRed[4][33][33];             // per-wave partials

    const int n  = blockIdx.x;
    const int b  = n / (SOUT * SOUT);
    const int yx = n % (SOUT * SOUT);
    const int y  = yx / SOUT;
    const int x  = yx % SOUT;

    const int t    = threadIdx.x;
    const int wave = t >> 6;            // 0..3
    const int o    = t & 31;
    const int woff = t >> 5;            // 0..7 = wave*2 + half
    const int half = woff & 1;

    // ---- stage 3x3 patch into LDS (coalesced float4) ----
    {
        const float4* src = reinterpret_cast<const float4*>(pose_in);
        float4* dst = reinterpret_cast<float4*>(sP);
        for (int u = t; u < NI * 4; u += 256) {   // 1152 float4
            const int k = u >> 7, idx = u & 127;  // cell, float4-within-cell
            const int ki = k / 3, kj = k - ki * 3;
            const int cell = (b * 14 + y + ki) * 14 + (x + kj);
            dst[u] = src[(size_t)cell * 128 + idx];
        }
        for (int u = t; u < NI; u += 256) {
            const int k = u >> 5, c = u & 31;
            const int ki = k / 3, kj = k - ki * 3;
            const int cell = (b * 14 + y + ki) * 14 + (x + kj);
            sA[u] = act_in[(size_t)cell * 32 + c];
        }
    }
    __syncthreads();

    const float* wbase = wmat + (size_t)(woff * 512 + o * 16);

    #pragma unroll 1
    for (int sweep = 0; sweep < 3; ++sweep) {
        // per-sweep register cache of the per-o stats (loop-invariant for this thread)
        float bias_r = 0.f;
        float i2r[PD], ngr[PD];
        if (sweep > 0) {
            bias_r = sBias[o];
            #pragma unroll
            for (int d = 0; d < PD; ++d) { i2r[d] = sInv2[o][d]; ngr[d] = sNeg[o][d]; }
        }

        float s1[PD], s2[PD];
        float s0 = 0.f;
        #pragma unroll
        for (int d = 0; d < PD; ++d) { s1[d] = 0.f; s2[d] = 0.f; }

        float WA0[16], WB0[16], WA1[16], WB1[16];
        loadW(wbase, WA0);
        loadW(wbase + 4096, WB0);

        // Body: process pair `pp` with (Wa,Wb), prefetch pair pp+1 into (Wna,Wnb).
#define PAIR_BODY(pp, Wa, Wb, Wna, Wnb)                                          \
        {                                                                        \
            const int _p = (pp);                                                 \
            if (_p < 17) {                                                       \
                loadW(wbase + (_p + 1) * 8192, Wna);                             \
                loadW(wbase + (_p + 1) * 8192 + 4096, Wnb);                      \
            }                                                                    \
            const int ia = _p * 16 + woff;                                       \
            const int ib = ia + 8;                                               \
            float va[16], vb[16];                                                \
            vote16(&sP[ia * PD], Wa, va);                                        \
            vote16(&sP[ib * PD], Wb, vb);                                        \
            const float aa = sA[ia], ab = sA[ib];                                \
            float rra, rrb;                                                      \
            if (sweep == 0) {                                                    \
                rra = aa * (1.0f / 32.0f);                                       \
                rrb = ab * (1.0f / 32.0f);                                       \
            } else {                                                             \
                float tsa = 0.f, tsb = 0.f;                                      \
                _Pragma("unroll")                                                \
                for (int d = 0; d < PD; ++d) {                                   \
                    tsa = fmaf(va[d], fmaf(va[d], i2r[d], ngr[d]), tsa);         \
                    tsb = fmaf(vb[d], fmaf(vb[d], i2r[d], ngr[d]), tsb);         \
                }                                                                \
                const float zza = bias_r - tsa, zzb = bias_r - tsb;              \
                float ma = zza, mb = zzb;                                        \
                ma = fmaxf(ma, SWZ(ma, 16)); mb = fmaxf(mb, SWZ(mb, 16));        \
                ma = fmaxf(ma, SWZ(ma, 8));  mb = fmaxf(mb, SWZ(mb, 8));         \
                ma = fmaxf(ma, SWZ(ma, 4));  mb = fmaxf(mb, SWZ(mb, 4));         \
                ma = fmaxf(ma, SWZ(ma, 2));  mb = fmaxf(mb, SWZ(mb, 2));         \
                ma = fmaxf(ma, SWZ(ma, 1));  mb = fmaxf(mb, SWZ(mb, 1));         \
                const float ea = __expf(zza - ma), eb = __expf(zzb - mb);        \
                float sa = ea, sb = eb;                                          \
                sa += SWZ(sa, 16); sb += SWZ(sb, 16);                            \
                sa += SWZ(sa, 8);  sb += SWZ(sb, 8);                             \
                sa += SWZ(sa, 4);  sb += SWZ(sb, 4);                             \
                sa += SWZ(sa, 2);  sb += SWZ(sb, 2);                             \
                sa += SWZ(sa, 1);  sb += SWZ(sb, 1);                             \
                rra = __fdividef(ea, sa) * aa;                                   \
                rrb = __fdividef(eb, sb) * ab;                                   \
            }                                                                    \
            s0 += rra + rrb;                                                     \
            _Pragma("unroll")                                                    \
            for (int d = 0; d < PD; ++d) {                                       \
                s1[d] = fmaf(rra, va[d], fmaf(rrb, vb[d], s1[d]));               \
                s2[d] = fmaf(rra * va[d], va[d], fmaf(rrb * vb[d], vb[d], s2[d]));\
            }                                                                    \
        }

        #pragma unroll 1
        for (int kk = 0; kk < 9; ++kk) {
            PAIR_BODY(2 * kk,     WA0, WB0, WA1, WB1);
            PAIR_BODY(2 * kk + 1, WA1, WB1, WA0, WB0);
        }
#undef PAIR_BODY

        // fold the two halves (same o) within each wave
        #pragma unroll
        for (int d = 0; d < PD; ++d) {
            s1[d] += __shfl_xor(s1[d], 32, 64);
            s2[d] += __shfl_xor(s2[d], 32, 64);
        }
        s0 += __shfl_xor(s0, 32, 64);

        if (half == 0) {
            #pragma unroll
            for (int d = 0; d < PD; ++d) {
                sRed[wave][d][o]      = s1[d];
                sRed[wave][16 + d][o] = s2[d];
            }
            sRed[wave][32][o] = s0;
        }
        __syncthreads();

        // ---- M-step: thread = (o, d-pair) over all 256 threads ----
        {
            const int oo = t >> 3, dp = t & 7, d0 = dp * 2;
            float S0 = 0.f, S1a = 0.f, S1b = 0.f, S2a = 0.f, S2b = 0.f;
            #pragma unroll
            for (int r = 0; r < 4; ++r) {
                S0  += sRed[r][32][oo];
                S1a += sRed[r][d0][oo];
                S1b += sRed[r][d0 + 1][oo];
                S2a += sRed[r][16 + d0][oo];
                S2b += sRed[r][17 + d0][oo];
            }
            const float inv = 1.f / S0;
            const float m0 = S1a * inv, m1 = S1b * inv;
            const float v0 = fmaxf(fmaf(-m0, m0, S2a * inv), 0.f);
            const float v1 = fmaxf(fmaf(-m1, m1, S2b * inv), 0.f);
            if (sweep == 2) {
                float2 pv; pv.x = m0; pv.y = m1;
                *reinterpret_cast<float2*>(out + (size_t)n * (OCAP * PD) + oo * PD + d0) = pv;
            }
            const float i20 = 0.5f / fmaxf(v0, 1e-30f);
            const float i21 = 0.5f / fmaxf(v1, 1e-30f);
            float llocal = __logf(sqrtf(v0) + EPSF) + __logf(sqrtf(v1) + EPSF);
            float c0l    = m0 * m0 * i20 + m1 * m1 * i21;
            if (sweep < 2) {
                sInv2[oo][d0]     = i20;
                sInv2[oo][d0 + 1] = i21;
                sNeg[oo][d0]      = -2.f * m0 * i20;
                sNeg[oo][d0 + 1]  = -2.f * m1 * i21;
            }
            #pragma unroll
            for (int msk = 1; msk <= 4; msk <<= 1) {
                llocal += __shfl_xor(llocal, msk, 8);
                c0l    += __shfl_xor(c0l,    msk, 8);
            }
            if (dp == 0) {
                const float lt   = llocal;
                const float cost = S0 * fmaf(16.f, beta_v[oo], lt);
                const float invtemp = 1.0f + (float)sweep;       // 1,2,3
                const float oact = 1.f / (1.f + __expf(-invtemp * (beta_a[oo] - cost)));
                if (sweep < 2)
                    sBias[oo] = __logf(oact + EPSF) - lt - c0l;
                else
                    out[POSE_OUT + (size_t)n * OCAP + oo] = oact;
            }
        }
        __syncthreads();
    }
}

} // namespace

extern "C" void kernel_launch(void* const* d_in, const int* in_sizes, int n_in,
                              void* d_out, int out_size, void* d_ws, size_t ws_size,
                              hipStream_t stream) {
    const float* pose_in = (const float*)d_in[0];
    const float* act_in  = (const float*)d_in[1];
    const float* wmat    = (const float*)d_in[2];
    const float* beta_v  = (const float*)d_in[3];
    const float* beta_a  = (const float*)d_in[4];
    float* out = (float*)d_out;

    caps_em_fused<<<dim3(NPOS), dim3(256), 0, stream>>>(
        pose_in, act_in, wmat, beta_v, beta_a, out);
}